// Round 2
// baseline (163.846 us; speedup 1.0000x reference)
//
#include <hip/hip_runtime.h>

// Problem: B=2, C=64, N=8192 (=8*32*32), D3=3C=192. All tensors FLOAT32
// (per reference). Internally we quantize W=exp(pq*pk) and pv to bf16 for
// the MFMA path; error ~0.4% rel on a gamma(~0.1)-scaled term, well under
// the 2%-of-max absmax threshold.
// ws layout: pq f32[2][8192] | pk f32[2][8192] | pv bf16[2][64][8192] (2.125 MB)

typedef __attribute__((ext_vector_type(8))) __bf16 bf16x8;
typedef __attribute__((ext_vector_type(4))) float  f32x4;

#define NN 8192
#define CC 64

// ---------------- Kernel 1: pq, pk, pv = wv @ [v;q;k] + biases ----------------
// grid 256 (= B * N/64), block 256 (4 waves). Thread = (n, cgroup of 16 c).
__global__ __launch_bounds__(256) void prep_kernel(
    const float* __restrict__ q, const float* __restrict__ k,
    const float* __restrict__ v,
    const float* __restrict__ wq, const float* __restrict__ bq,
    const float* __restrict__ wk, const float* __restrict__ bk,
    const float* __restrict__ wv, const float* __restrict__ bv,
    float* __restrict__ pq, float* __restrict__ pk, __bf16* __restrict__ pv)
{
    __shared__ __align__(16) float wvT[192][64];   // transposed so wave reads broadcast
    __shared__ float wq_s[64], wk_s[64], bv_s[64];

    int t = threadIdx.x;
    int b = blockIdx.x >> 7;
    int n0 = (blockIdx.x & 127) << 6;

    for (int i = t; i < 64 * 192; i += 256) {
        int c = i / 192, d = i - c * 192;
        wvT[d][c] = wv[i];                         // wv is [c][d] row-major
    }
    if (t < 64) { wq_s[t] = wq[t]; wk_s[t] = wk[t]; bv_s[t] = bv[t]; }
    __syncthreads();

    int lane = t & 63, cg = t >> 6;                // cg uniform per wave
    int n = n0 + lane;
    size_t bo = (size_t)b * CC * NN;

    f32x4 a4[4];
    for (int j = 0; j < 4; j++) a4[j] = (f32x4){0.f, 0.f, 0.f, 0.f};
    float pqa = 0.f, pka = 0.f;

    const f32x4* wrow;
    // part 0: v (d = 0..63)
    {
        const float* sp = v + bo + n;
        for (int dc = 0; dc < 64; dc++) {
            float x = sp[(size_t)dc * NN];
            wrow = (const f32x4*)&wvT[dc][cg * 16];          // broadcast (same addr per wave)
            #pragma unroll
            for (int j = 0; j < 4; j++) a4[j] += x * wrow[j];
        }
    }
    // part 1: q (d = 64..127), also pq partial
    {
        const float* sp = q + bo + n;
        for (int dc = 0; dc < 64; dc++) {
            float x = sp[(size_t)dc * NN];
            wrow = (const f32x4*)&wvT[64 + dc][cg * 16];
            #pragma unroll
            for (int j = 0; j < 4; j++) a4[j] += x * wrow[j];
            pqa += x * wq_s[dc];
        }
    }
    // part 2: k (d = 128..191), also pk partial
    {
        const float* sp = k + bo + n;
        for (int dc = 0; dc < 64; dc++) {
            float x = sp[(size_t)dc * NN];
            wrow = (const f32x4*)&wvT[128 + dc][cg * 16];
            #pragma unroll
            for (int j = 0; j < 4; j++) a4[j] += x * wrow[j];
            pka += x * wk_s[dc];
        }
    }

    __bf16* dst = pv + bo + n;
    #pragma unroll
    for (int j = 0; j < 16; j++) {
        int c = cg * 16 + j;
        float o = a4[j >> 2][j & 3] + bv_s[c];
        dst[(size_t)c * NN] = (__bf16)o;
    }
    if (cg == 0) pq[b * NN + n] = pqa + bq[0];
    if (cg == 1) pk[b * NN + n] = pka + bk[0];
}

// ---------------- Kernel 2: attention GEMM + normalize + epilogue ----------------
// grid 512 (= B * N/32), block 256 (4 waves), ~43KB LDS -> 2 blocks/CU.
// Block owns 32 m rows x all 64 c. Waves K-split the n (key) range.
// W[m][n]=exp(s_m*t_n) is computed IN-REGISTER directly in MFMA A-frag layout
// (A[m=lane&15][k=quad*8+j]); B-frags (pv[c][n], 8 contig bf16) load straight
// from global (L2-resident). No barriers in the main loop. Softmax max-
// subtraction cancels exactly in the exp ratio (|s*t|<=~16, no overflow).
__global__ __launch_bounds__(256, 2) void attn_kernel(
    const float* __restrict__ pq, const float* __restrict__ pk,
    const __bf16* __restrict__ pv, const float* __restrict__ v,
    const float* __restrict__ gamma, float* __restrict__ out)
{
    __shared__ __align__(16) float t_s[NN];       // full pk row: 32 KB
    __shared__ float s_s[32];
    __shared__ __align__(16) float o_s[32][65];   // padded cross-wave reduce buf
    __shared__ float z_s[32][16];
    __shared__ float zinv_s[32];

    int t = threadIdx.x;
    int b = blockIdx.x >> 8;
    int m0 = (blockIdx.x & 255) << 5;
    int lane = t & 63, wid = t >> 6;
    int quad = lane >> 4, cl = lane & 15;

    {   // stage pk[b][:] into LDS, coalesced float4
        const f32x4* src = (const f32x4*)(pk + (size_t)b * NN);
        f32x4* dst = (f32x4*)t_s;
        for (int i = t; i < NN / 4; i += 256) dst[i] = src[i];
    }
    if (t < 32) s_s[t] = pq[b * NN + m0 + t];
    __syncthreads();

    float s0 = s_s[cl], s1 = s_s[16 + cl];        // per-lane query scalars (2 m-frags)
    const __bf16* pvb = pv + (size_t)b * CC * NN;

    f32x4 acc[2][4];
    #pragma unroll
    for (int ai = 0; ai < 2; ai++)
        #pragma unroll
        for (int ci = 0; ci < 4; ci++) acc[ai][ci] = (f32x4){0.f, 0.f, 0.f, 0.f};
    float z0 = 0.f, z1 = 0.f;

    for (int n0 = 0; n0 < NN; n0 += 128) {
        int nb = n0 + wid * 32 + quad * 8;        // this lane's k-slice (K-split by wave)
        // B-frags: pv rows, 16B each — issue early to hide latency under exp VALU
        bf16x8 b0 = *(const bf16x8*)(pvb + (size_t)(cl)      * NN + nb);
        bf16x8 b1 = *(const bf16x8*)(pvb + (size_t)(16 + cl) * NN + nb);
        bf16x8 b2 = *(const bf16x8*)(pvb + (size_t)(32 + cl) * NN + nb);
        bf16x8 b3 = *(const bf16x8*)(pvb + (size_t)(48 + cl) * NN + nb);
        // key values for this slice (LDS broadcast within quad)
        f32x4 t01 = *(const f32x4*)&t_s[nb];
        f32x4 t23 = *(const f32x4*)&t_s[nb + 4];
        float e[8], f[8];
        #pragma unroll
        for (int j = 0; j < 4; j++) {
            e[j]     = __expf(s0 * t01[j]);  e[4 + j] = __expf(s0 * t23[j]);
            f[j]     = __expf(s1 * t01[j]);  f[4 + j] = __expf(s1 * t23[j]);
        }
        bf16x8 a0, a1;
        #pragma unroll
        for (int j = 0; j < 8; j++) {
            a0[j] = (__bf16)e[j];  a1[j] = (__bf16)f[j];
            z0 += e[j];            z1 += f[j];
        }
        acc[0][0] = __builtin_amdgcn_mfma_f32_16x16x32_bf16(a0, b0, acc[0][0], 0, 0, 0);
        acc[0][1] = __builtin_amdgcn_mfma_f32_16x16x32_bf16(a0, b1, acc[0][1], 0, 0, 0);
        acc[0][2] = __builtin_amdgcn_mfma_f32_16x16x32_bf16(a0, b2, acc[0][2], 0, 0, 0);
        acc[0][3] = __builtin_amdgcn_mfma_f32_16x16x32_bf16(a0, b3, acc[0][3], 0, 0, 0);
        acc[1][0] = __builtin_amdgcn_mfma_f32_16x16x32_bf16(a1, b0, acc[1][0], 0, 0, 0);
        acc[1][1] = __builtin_amdgcn_mfma_f32_16x16x32_bf16(a1, b1, acc[1][1], 0, 0, 0);
        acc[1][2] = __builtin_amdgcn_mfma_f32_16x16x32_bf16(a1, b2, acc[1][2], 0, 0, 0);
        acc[1][3] = __builtin_amdgcn_mfma_f32_16x16x32_bf16(a1, b3, acc[1][3], 0, 0, 0);
    }

    // Z partials: one slot per (m, wave*4+quad)
    z_s[cl][wid * 4 + quad]      = z0;
    z_s[16 + cl][wid * 4 + quad] = z1;

    // cross-wave accumulator reduce (waves hold disjoint K-partial sums of same tile)
    for (int w = 0; w < 4; w++) {
        __syncthreads();
        if (wid == w) {
            #pragma unroll
            for (int ai = 0; ai < 2; ai++)
                #pragma unroll
                for (int ci = 0; ci < 4; ci++)
                    #pragma unroll
                    for (int r = 0; r < 4; r++) {
                        int m = ai * 16 + quad * 4 + r;   // D row = quad*4+reg (m91)
                        int c = ci * 16 + cl;             // D col = lane&15
                        if (w == 0) o_s[m][c] = acc[ai][ci][r];
                        else        o_s[m][c] += acc[ai][ci][r];
                    }
        }
    }
    __syncthreads();
    if (t < 32) {
        float zz = 0.f;
        #pragma unroll
        for (int p = 0; p < 16; p++) zz += z_s[t][p];
        zinv_s[t] = 1.0f / zz;
    }
    __syncthreads();

    // epilogue: out[b][c][m] = gamma * o/Z + v, f32 vector stores
    float g = gamma[0];
    int c = t >> 2, ms = (t & 3) << 3;
    size_t base = (size_t)b * CC * NN + (size_t)c * NN + m0 + ms;
    const f32x4* vv = (const f32x4*)(v + base);
    f32x4* op = (f32x4*)(out + base);
    #pragma unroll
    for (int h = 0; h < 2; h++) {
        f32x4 vvh = vv[h];
        f32x4 ovh;
        #pragma unroll
        for (int i = 0; i < 4; i++) {
            int m = ms + h * 4 + i;
            ovh[i] = g * o_s[m][c] * zinv_s[m] + vvh[i];
        }
        op[h] = ovh;
    }
}

extern "C" void kernel_launch(void* const* d_in, const int* in_sizes, int n_in,
                              void* d_out, int out_size, void* d_ws, size_t ws_size,
                              hipStream_t stream)
{
    const float* q     = (const float*)d_in[0];
    const float* k     = (const float*)d_in[1];
    const float* v     = (const float*)d_in[2];
    const float* wq    = (const float*)d_in[3];
    const float* bq    = (const float*)d_in[4];
    const float* wk    = (const float*)d_in[5];
    const float* bk    = (const float*)d_in[6];
    const float* wv    = (const float*)d_in[7];
    const float* bv    = (const float*)d_in[8];
    const float* gamma = (const float*)d_in[9];

    float*  pqw = (float*)d_ws;                       // 2*8192 f32
    float*  pkw = pqw + 2 * NN;                       // 2*8192 f32
    __bf16* pvw = (__bf16*)(pkw + 2 * NN);            // 2*64*8192 bf16

    prep_kernel<<<256, 256, 0, stream>>>(q, k, v, wq, bq, wk, bk, wv, bv,
                                         pqw, pkw, pvw);
    attn_kernel<<<512, 256, 0, stream>>>(pqw, pkw, pvw, v, gamma, (float*)d_out);
}